// Round 15
// baseline (208.086 us; speedup 1.0000x reference)
//
#include <hip/hip_runtime.h>

// ---------------------------------------------------------------------------
// Soft decision tree forward (all-f16), round 15: 32-row mega-kernel,
// 2 blocks/CU co-residency.
//   d = sigmoid(X @ T^T); leaf probs = depth-10 path products;
//   out = softmax(probs @ L)
//
// vs round 14 (all algebra preserved):
//  - block = 32 rows, 512 threads / 8 waves (wave = 32 rows x 128 cols),
//    grid 1024. LDS one 66KB time-shared region (X -> d -> packed probs)
//    -> 2 blocks/CU; neighboring blocks' phases overlap (K-loop hides the
//    other block's HBM phase A / VALU expansion / epilogue).
//  - each gemm = two N-passes with acc[2][4] + 4-frag b reg-dbuf (keeps
//    unified VGPR <= 128 for 16 waves/CU). Same total traffic; per-output
//    kt-accumulation order unchanged.
// Canary: absmax must read exactly 0.0004882812.
// ---------------------------------------------------------------------------

typedef unsigned short u16;
typedef unsigned short u16x8 __attribute__((ext_vector_type(8)));
typedef _Float16 f16;
typedef _Float16 f16x8 __attribute__((ext_vector_type(8)));
typedef float f32x4 __attribute__((ext_vector_type(4)));

#define BATCH 32768
#define DIM   1024
#define NPAD  1024
#define DSTRIDE 2112

#define BARRIER()  asm volatile("s_barrier" ::: "memory")

// ---- f16 helpers ----
__device__ __forceinline__ u16 f2h(float f) {
    union { f16 h; u16 u; } v; v.h = (f16)f; return v.u;
}
__device__ __forceinline__ float h2f(u16 u) {
    union { u16 u; f16 h; } v; v.u = u; return (float)v.h;
}

#define MFMA16(a, b, c) __builtin_amdgcn_mfma_f32_16x16x32_f16(a, b, c, 0, 0, 0)

// ---------------------------------------------------------------------------
// prep: thresholds -> Bpk1 fragment-packed f16 (node row 1023 = 0; frozen)
// ---------------------------------------------------------------------------
__global__ __launch_bounds__(256) void prep_tp(const float* __restrict__ t,
                                               u16* __restrict__ Bpk1) {
    int o = (blockIdx.x * 256 + threadIdx.x) * 4;
    int n16  = o >> 14;
    int kt   = (o >> 9) & 31;
    int lane = (o >> 3) & 63;
    int j0   = o & 7;
    int mr = lane & 15, kg = lane >> 4;
    int node = n16 * 16 + mr;
    int k0  = kt * 32 + kg * 8 + j0;
    ushort4 v = make_ushort4(0, 0, 0, 0);
    if (node < 1023) {
        const float* src = t + (size_t)node * 1024 + k0;
        v.x = f2h(src[0]); v.y = f2h(src[1]);
        v.z = f2h(src[2]); v.w = f2h(src[3]);
    }
    *(ushort4*)&Bpk1[o] = v;
}

// ---------------------------------------------------------------------------
// prep: L -> BpkL fragment-packed f16 (frozen)
// ---------------------------------------------------------------------------
__global__ __launch_bounds__(256) void prep_lt(const float* __restrict__ L,
                                               u16* __restrict__ BpkL) {
    int o = (blockIdx.x * 256 + threadIdx.x) * 4;
    int b16  = o >> 14;
    int kt   = (o >> 9) & 31;
    int lane = (o >> 3) & 63;
    int j0   = o & 7;
    int mr = lane & 15, kg = lane >> 4;
    int col = b16 * 16 + mr;
    int k0  = kt * 32 + kg * 8 + j0;
    ushort4 v;
    v.x = f2h(L[(size_t)(k0 + 0) * 1024 + col]);
    v.y = f2h(L[(size_t)(k0 + 1) * 1024 + col]);
    v.z = f2h(L[(size_t)(k0 + 2) * 1024 + col]);
    v.w = f2h(L[(size_t)(k0 + 3) * 1024 + col]);
    *(ushort4*)&BpkL[o] = v;
}

// ---------------------------------------------------------------------------
// MEGA KERNEL (32 rows / block, 8 waves, two N-passes per gemm)
// ---------------------------------------------------------------------------
__global__ __launch_bounds__(512, 4) void megak(
    const float* __restrict__ X, const u16* __restrict__ Bpk1,
    const u16* __restrict__ BpkL, float* __restrict__ out)
{
    __shared__ __align__(16) char lds[67584];
    const int t = threadIdx.x, wid = t >> 6, lane = t & 63;
    const int mr = lane & 15, kg = lane >> 4;
    const int rb = blockIdx.x * 32;
    const int fq = kg * 4;

    // B1 bases: wave owns cols wid*128; pass p covers n16-blocks wid*8+p*4+n
    const u16* bb1p0[4];
    const u16* bb1p1[4];
#pragma unroll
    for (int n = 0; n < 4; ++n) {
        bb1p0[n] = Bpk1 + (size_t)(wid * 8 + n) * 16384 + (unsigned)lane * 8u;
        bb1p1[n] = Bpk1 + (size_t)(wid * 8 + 4 + n) * 16384 + (unsigned)lane * 8u;
    }

    f16x8 bA[4], bB[4];

    // ---------------- phase A: X f32 -> f16 LDS [32][2048B] ----------------
    // row byte w holds global f16-k-byte (w ^ ((row&7)<<4));
    // chunk c (4 rows, 8KB): dest = lds + c*8192 + t*16.
    {
        const unsigned woff = (unsigned)((wid & 1) * 1024 + lane * 16);
        const int rowbase = wid >> 1;
        float4 xlo[8], xhi[8];
#pragma unroll
        for (int c = 0; c < 8; ++c) {
            int row = c * 4 + rowbase;
            unsigned key = (unsigned)(row & 7) << 4;
            const float* src = X + (size_t)(rb + row) * 1024 + ((woff ^ key) >> 1);
            xlo[c] = *(const float4*)src;
            xhi[c] = *(const float4*)(src + 4);
        }
        // b1 pass-0 b(0) issued AFTER X loads (youngest) -> stays in flight
#pragma unroll
        for (int n = 0; n < 4; ++n) bA[n] = *(const f16x8*)(bb1p0[n]);
#pragma unroll
        for (int c = 0; c < 8; ++c) {
            u16x8 h;
            h[0] = f2h(xlo[c].x); h[1] = f2h(xlo[c].y);
            h[2] = f2h(xlo[c].z); h[3] = f2h(xlo[c].w);
            h[4] = f2h(xhi[c].x); h[5] = f2h(xhi[c].y);
            h[6] = f2h(xhi[c].z); h[7] = f2h(xhi[c].w);
            *(u16x8*)(lds + c * 8192 + t * 16) = h;
        }
    }
    asm volatile("s_waitcnt lgkmcnt(0)" ::: "memory");
    BARRIER();

    // ---------------- phase B: gemm1, two N-passes, barrier-free ----------
    const unsigned keyA1 = (unsigned)(mr & 7) << 4;
    unsigned offA1[2];
#pragma unroll
    for (int m = 0; m < 2; ++m) offA1[m] = (unsigned)((m * 16 + mr) * 2048);

    f32x4 accA[2][4], accB[2][4];
#pragma unroll
    for (int m = 0; m < 2; ++m)
#pragma unroll
        for (int n = 0; n < 4; ++n) {
            accA[m][n] = (f32x4){0.f, 0.f, 0.f, 0.f};
            accB[m][n] = (f32x4){0.f, 0.f, 0.f, 0.f};
        }

    auto g1step = [&](int kt, const u16* const (&bb)[4],
                      f16x8 (&bu)[4], f16x8 (&bl)[4], f32x4 (&acc)[2][4]) {
        if (kt + 1 < 32) {
#pragma unroll
            for (int n = 0; n < 4; ++n)
                bl[n] = *(const f16x8*)(bb[n] + (unsigned)(kt + 1) * 512u);
        }
        const unsigned ko = ((unsigned)(kt * 64) + (unsigned)kg * 16u) ^ keyA1;
        f16x8 a[2];
#pragma unroll
        for (int m = 0; m < 2; ++m)
            a[m] = *(const f16x8*)(lds + offA1[m] + ko);
        __builtin_amdgcn_s_setprio(1);
#pragma unroll
        for (int m = 0; m < 2; ++m)
#pragma unroll
            for (int n = 0; n < 4; ++n)
                acc[m][n] = MFMA16(a[m], bu[n], acc[m][n]);
        __builtin_amdgcn_s_setprio(0);
    };

#pragma unroll 1
    for (int k2 = 0; k2 < 16; ++k2) {
        g1step(2 * k2, bb1p0, bA, bB, accA);
        g1step(2 * k2 + 1, bb1p0, bB, bA, accA);
    }
    // pass 1
#pragma unroll
    for (int n = 0; n < 4; ++n) bA[n] = *(const f16x8*)(bb1p1[n]);
#pragma unroll 1
    for (int k2 = 0; k2 < 16; ++k2) {
        g1step(2 * k2, bb1p1, bA, bB, accB);
        g1step(2 * k2 + 1, bb1p1, bB, bA, accB);
    }

    // ---------------- phase C: sigmoid -> d into LDS [32][2112B] ----------
    __syncthreads();     // all waves done reading X-LDS
#pragma unroll
    for (int m = 0; m < 2; ++m)
#pragma unroll
        for (int j = 0; j < 4; ++j) {
            int row = m * 16 + fq + j;
            unsigned wkey = ((unsigned)((row >> 2) & 3)) << 4;
            char* drow = lds + row * DSTRIDE;
#pragma unroll
            for (int n = 0; n < 4; ++n) {
                int colA = wid * 128 + n * 16 + mr;
                float dA = 1.0f / (1.0f + __expf(-accA[m][n][j]));
                *(u16*)(drow + ((2u + 2u * (unsigned)colA) ^ wkey)) = f2h(dA);
                float dB = 1.0f / (1.0f + __expf(-accB[m][n][j]));
                *(u16*)(drow + ((2u + 2u * (unsigned)(colA + 64)) ^ wkey)) = f2h(dB);
            }
        }
    __syncthreads();     // d complete

    // ---------------- phase D: tree expansion (d from LDS) ----------------
    u16x8 pk[4][2];
#pragma unroll
    for (int r = 0; r < 4; ++r) {
        const int lrow = wid * 4 + r;
        const char* dro = lds + lrow * DSTRIDE;
        const unsigned dkey = ((unsigned)((lrow >> 2) & 3)) << 4;
        const int l = lane;

        float prod = 1.0f;
#pragma unroll
        for (int lev = 0; lev < 6; lev++) {
            int node = (1 << lev) - 1 + (l >> (6 - lev));
            int bit  = (l >> (5 - lev)) & 1;
            float v = h2f(*(const u16*)(dro + ((2u + 2u * (unsigned)node) ^ dkey)));
            prod *= bit ? (1.0f - v) : v;
        }
        float d6 = h2f(*(const u16*)(dro + ((2u + 2u * (unsigned)(63 + l)) ^ dkey)));
        ushort2 p7 = *(const ushort2*)(dro + ((256u + 4u * (unsigned)l) ^ dkey));
        ushort4 p8 = *(const ushort4*)(dro + ((512u + 8u * (unsigned)l) ^ dkey));
        u16x8   p9 = *(const u16x8*)(dro + ((1024u + 16u * (unsigned)l) ^ dkey));
        float d7[2] = {h2f(p7.x), h2f(p7.y)};
        float d8[4] = {h2f(p8.x), h2f(p8.y), h2f(p8.z), h2f(p8.w)};
        float d9[8];
#pragma unroll
        for (int j = 0; j < 8; j++) d9[j] = h2f(p9[j]);

        u16 outv[16];
#pragma unroll
        for (int j = 0; j < 16; j++) {
            float f6 = (j >> 3) ? (1.0f - d6) : d6;
            float v7 = d7[j >> 3];  float f7 = ((j >> 2) & 1) ? (1.0f - v7) : v7;
            float v8 = d8[j >> 2];  float f8 = ((j >> 1) & 1) ? (1.0f - v8) : v8;
            float v9 = d9[j >> 1];  float f9 = (j & 1) ? (1.0f - v9) : v9;
            outv[j] = f2h(prod * f6 * f7 * f8 * f9);
        }
        pk[r][0] = (u16x8){outv[0], outv[1], outv[2], outv[3],
                           outv[4], outv[5], outv[6], outv[7]};
        pk[r][1] = (u16x8){outv[8], outv[9], outv[10], outv[11],
                           outv[12], outv[13], outv[14], outv[15]};
    }
    __syncthreads();     // all d reads done before probs overwrite

    // packed probs write, slot-XOR (kt&7)
    {
        const int ktw = lane >> 1, kg0 = (lane & 1) * 2;
        const unsigned K = (unsigned)(ktw & 7);
#pragma unroll
        for (int r = 0; r < 4; ++r) {
            const int lrow = wid * 4 + r;
            const int m = lrow >> 4, mrr = lrow & 15;
            char* base = lds + (((ktw << 1) + m) << 10);
            unsigned s0 = ((unsigned)(kg0 * 16 + mrr)) ^ K;
            unsigned s1 = ((unsigned)((kg0 + 1) * 16 + mrr)) ^ K;
            *(u16x8*)(base + s0 * 16) = pk[r][0];
            *(u16x8*)(base + s1 * 16) = pk[r][1];
        }
    }
    __syncthreads();     // probs complete

    // ---------------- phase E: gemm2, two N-passes, barrier-free ----------
    const u16* bb2p0 = BpkL + (size_t)(wid * 8) * 16384 + (unsigned)lane * 8u;
    const u16* bb2p1 = bb2p0 + (size_t)4 * 16384;

    f32x4 acc2A[2][4], acc2B[2][4];
#pragma unroll
    for (int m = 0; m < 2; ++m)
#pragma unroll
        for (int n = 0; n < 4; ++n) {
            acc2A[m][n] = (f32x4){0.f, 0.f, 0.f, 0.f};
            acc2B[m][n] = (f32x4){0.f, 0.f, 0.f, 0.f};
        }

    auto g2step = [&](int kt, const u16* bb,
                      f16x8 (&bu)[4], f16x8 (&bl)[4], f32x4 (&acc)[2][4]) {
        if (kt + 1 < 32) {
#pragma unroll
            for (int n = 0; n < 4; ++n)
                bl[n] = *(const f16x8*)(bb + n * 16384 + (unsigned)(kt + 1) * 512u);
        }
        const unsigned sl = ((unsigned)(lane ^ (kt & 7))) << 4;
        f16x8 a[2];
#pragma unroll
        for (int m = 0; m < 2; ++m)
            a[m] = *(const f16x8*)(lds + (((kt << 1) + m) << 10) + sl);
        __builtin_amdgcn_s_setprio(1);
#pragma unroll
        for (int m = 0; m < 2; ++m)
#pragma unroll
            for (int n = 0; n < 4; ++n)
                acc[m][n] = MFMA16(a[m], bu[n], acc[m][n]);
        __builtin_amdgcn_s_setprio(0);
    };

#pragma unroll
    for (int n = 0; n < 4; ++n) bA[n] = *(const f16x8*)(bb2p0 + n * 16384);
#pragma unroll 1
    for (int k2 = 0; k2 < 16; ++k2) {
        g2step(2 * k2, bb2p0, bA, bB, acc2A);
        g2step(2 * k2 + 1, bb2p0, bB, bA, acc2A);
    }
#pragma unroll
    for (int n = 0; n < 4; ++n) bA[n] = *(const f16x8*)(bb2p1 + n * 16384);
#pragma unroll 1
    for (int k2 = 0; k2 < 16; ++k2) {
        g2step(2 * k2, bb2p1, bA, bB, acc2B);
        g2step(2 * k2 + 1, bb2p1, bB, bA, acc2B);
    }

    __syncthreads();     // all probs reads done before red reuse

    // ---------------- phase F: in-register softmax ----------------
    // thread rows: r(m,j) = m*16 + kg*4 + j; cols: wid*128 + (0|64) + n*16+mr
    float* red  = (float*)lds;            // [32][8] max
    float* red2 = (float*)(lds + 4096);   // [32][8] sum

    float mx[2][4];
#pragma unroll
    for (int m = 0; m < 2; ++m)
#pragma unroll
        for (int j = 0; j < 4; ++j) {
            float v = acc2A[m][0][j];
#pragma unroll
            for (int n = 1; n < 4; ++n) v = fmaxf(v, acc2A[m][n][j]);
#pragma unroll
            for (int n = 0; n < 4; ++n) v = fmaxf(v, acc2B[m][n][j]);
#pragma unroll
            for (int off = 1; off < 16; off <<= 1)
                v = fmaxf(v, __shfl_xor(v, off));
            mx[m][j] = v;
        }
    if (mr == 0) {
#pragma unroll
        for (int m = 0; m < 2; ++m)
#pragma unroll
            for (int j = 0; j < 4; ++j)
                red[(m * 16 + fq + j) * 8 + wid] = mx[m][j];
    }
    __syncthreads();
    if (t < 32) {
        float v = red[t * 8];
#pragma unroll
        for (int w = 1; w < 8; ++w) v = fmaxf(v, red[t * 8 + w]);
        red[t * 8] = v;
    }
    __syncthreads();

    float sm[2][4];
#pragma unroll
    for (int m = 0; m < 2; ++m)
#pragma unroll
        for (int j = 0; j < 4; ++j) {
            float M = red[(m * 16 + fq + j) * 8];
            float s = 0.f;
#pragma unroll
            for (int n = 0; n < 4; ++n) {
                float e = __expf(acc2A[m][n][j] - M);
                acc2A[m][n][j] = e;
                s += e;
            }
#pragma unroll
            for (int n = 0; n < 4; ++n) {
                float e = __expf(acc2B[m][n][j] - M);
                acc2B[m][n][j] = e;
                s += e;
            }
#pragma unroll
            for (int off = 1; off < 16; off <<= 1)
                s += __shfl_xor(s, off);
            sm[m][j] = s;
        }
    if (mr == 0) {
#pragma unroll
        for (int m = 0; m < 2; ++m)
#pragma unroll
            for (int j = 0; j < 4; ++j)
                red2[(m * 16 + fq + j) * 8 + wid] = sm[m][j];
    }
    __syncthreads();
    if (t < 32) {
        float v = 0.f;
#pragma unroll
        for (int w = 0; w < 8; ++w) v += red2[t * 8 + w];
        red2[t * 8] = 1.0f / v;
    }
    __syncthreads();

#pragma unroll
    for (int m = 0; m < 2; ++m)
#pragma unroll
        for (int j = 0; j < 4; ++j) {
            int grow = rb + m * 16 + fq + j;
            float inv = red2[(m * 16 + fq + j) * 8];
#pragma unroll
            for (int n = 0; n < 4; ++n) {
                int gcolA = wid * 128 + n * 16 + mr;
                out[(size_t)grow * 1024 + gcolA] = acc2A[m][n][j] * inv;
                out[(size_t)grow * 1024 + gcolA + 64] = acc2B[m][n][j] * inv;
            }
        }
}

// ---------------------------------------------------------------------------
extern "C" void kernel_launch(void* const* d_in, const int* in_sizes, int n_in,
                              void* d_out, int out_size, void* d_ws, size_t ws_size,
                              hipStream_t stream) {
    const float* x  = (const float*)d_in[0];
    const float* ft = (const float*)d_in[1];
    const float* lp = (const float*)d_in[2];
    float* out = (float*)d_out;
    char* ws = (char*)d_ws;

    // ws layout: Bpk1 2Mi | BpkL 2Mi
    u16* Bpk1 = (u16*)ws;
    u16* BpkL = Bpk1 + (size_t)NPAD * DIM;

    prep_tp<<<1024, 256, 0, stream>>>(ft, Bpk1);
    prep_lt<<<1024, 256, 0, stream>>>(lp, BpkL);
    megak<<<1024, 512, 0, stream>>>(x, Bpk1, BpkL, out);
}